// Round 16
// baseline (294.295 us; speedup 1.0000x reference)
//
#include <hip/hip_runtime.h>
#include <hip/hip_bf16.h>

// Problem constants
#define N_ATOMS 262144
#define B_SZ    64
#define H_DIM   256
#define R_DIM   512

#define ROWS_PB 512
#define NSETS   32                          // 16-row sets per block
#define NBLOCKS (N_ATOMS / ROWS_PB)         // 512

typedef __attribute__((ext_vector_type(8))) short bf16x8;
typedef __attribute__((ext_vector_type(4))) float f32x4;

static __device__ __forceinline__ short f2bf(float f) {
  unsigned u = __builtin_bit_cast(unsigned, f);
  u = (u + 0x7FFFu + ((u >> 16) & 1u)) >> 16;   // RNE
  return (short)u;
}

// v_cvt_pk_bf16_f32 (no builtin on gfx950 — inline asm, m240)
static __device__ __forceinline__ unsigned cvtpk(float lo, float hi) {
  unsigned r;
  asm("v_cvt_pk_bf16_f32 %0, %1, %2" : "=v"(r) : "v"(lo), "v"(hi));
  return r;
}

static __device__ __forceinline__ bf16x8 pack8(f32x4 a0, f32x4 a1) {
  unsigned u0 = cvtpk(a0[0], a0[1]);
  unsigned u1 = cvtpk(a0[2], a0[3]);
  unsigned u2 = cvtpk(a1[0], a1[1]);
  unsigned u3 = cvtpk(a1[2], a1[3]);
  bf16x8 v;
  v[0] = (short)(u0 & 0xFFFF); v[1] = (short)(u0 >> 16);
  v[2] = (short)(u1 & 0xFFFF); v[3] = (short)(u1 >> 16);
  v[4] = (short)(u2 & 0xFFFF); v[5] = (short)(u2 >> 16);
  v[6] = (short)(u3 & 0xFFFF); v[7] = (short)(u3 >> 16);
  return v;
}

// ---------------------------------------------------------------------------
// Prep kernel (unchanged):
//   blocks [0,64):  pooled[b][o] = bl[o] + retj . Wl[o,256:512]
//   blocks [64,80): Bbf fragment-order bf16 conversion of Wl[:, :256]
// ---------------------------------------------------------------------------
__global__ __launch_bounds__(1024) void prep_kernel(
    const float* __restrict__ rf, const float* __restrict__ Wp,
    const float* __restrict__ bp, const float* __restrict__ Wl,
    const float* __restrict__ bl, float* __restrict__ pooled,
    short* __restrict__ Bbf) {
  int t = threadIdx.x;
  if (blockIdx.x >= B_SZ) {
    int base = (blockIdx.x - B_SZ) * 4096 + t * 4;
#pragma unroll
    for (int q = 0; q < 4; ++q) {
      int idx  = base + q;
      int j    = idx & 7;
      int lane = (idx >> 3) & 63;
      int ks   = (idx >> 9) & 7;
      int ct   = idx >> 12;
      int o    = ct * 16 + (lane & 15);
      int k    = ks * 32 + ((lane >> 4) << 3) + j;
      Bbf[idx] = f2bf(Wl[o * (2 * H_DIM) + k]);
    }
    return;
  }

  __shared__ float meanr[R_DIM];
  __shared__ float retj[H_DIM];
  int b    = blockIdx.x;
  int lane = t & 63;
  int w    = t >> 6;            // 16 waves

  if (t < R_DIM) {
    float s = 0.f;
    const float* p = rf + (long)b * 16 * R_DIM + t;
#pragma unroll
    for (int k = 0; k < 16; ++k) s += p[k * R_DIM];
    meanr[t] = s * (1.f / 16.f);
  }
  __syncthreads();

  {
    f32x4 m0 = *(const f32x4*)&meanr[lane * 8];
    f32x4 m1 = *(const f32x4*)&meanr[lane * 8 + 4];
#pragma unroll
    for (int jj = 0; jj < 16; ++jj) {
      int j = w * 16 + jj;
      const f32x4* wp = (const f32x4*)(Wp + (long)j * R_DIM + lane * 8);
      f32x4 w0 = wp[0], w1 = wp[1];
      float s = m0[0]*w0[0] + m0[1]*w0[1] + m0[2]*w0[2] + m0[3]*w0[3]
              + m1[0]*w1[0] + m1[1]*w1[1] + m1[2]*w1[2] + m1[3]*w1[3];
#pragma unroll
      for (int d = 1; d < 64; d <<= 1) s += __shfl_xor(s, d);
      if (lane == 0) retj[j] = s + bp[j];
    }
  }
  __syncthreads();

  {
    f32x4 r0 = *(const f32x4*)&retj[lane * 4];
#pragma unroll
    for (int oo = 0; oo < 16; ++oo) {
      int o = w * 16 + oo;
      f32x4 wv = *(const f32x4*)(Wl + (long)o * (2 * H_DIM) + H_DIM + lane * 4);
      float s = r0[0]*wv[0] + r0[1]*wv[1] + r0[2]*wv[2] + r0[3]*wv[3];
#pragma unroll
      for (int d = 1; d < 64; d <<= 1) s += __shfl_xor(s, d);
      if (lane == 0) pooled[b * H_DIM + o] = s + bl[o];
    }
  }
}

// ---------------------------------------------------------------------------
// GEMM: out[n][o] = sum_k h[n][k]*Wl[o][k] + pooled[batch[n]][o]
// BARRIER-FREE MAIN LOOP (the one factor all 144-µs variants shared and
// probe_rw (92.5 µs/pass, no barriers) lacked).
//
// 512 blocks x 512 threads (8 waves); block owns 512 rows = 32 sets of 16.
// Every wave processes every set: loads its own MFMA A-fragments straight
// from global (r3/probe_str pattern — probe-verified at ceiling BW):
// lane reads h[g0+(lane&15)][ (lane>>4)*8 + ks*32 ..+7 ] as 2 dwordx4.
// The 8 waves read the SAME addresses -> L1/L2 broadcast serves 7 of 8
// (L2 demand ~31 GB/s/CU << 135); HBM still fetches each line once.
// B strips (col-tiles 2w, 2w+1) in registers. pv/batch staged in LDS ONCE
// (prologue, single __syncthreads) -> per-set pv = ds_read, no dependent
// VMEM loads in the loop. No manual waitcnts: every load has a register
// dest, so the compiler's per-use vmcnt waits are exact and minimal.
//
// Software pipeline, 2-ks batch granularity: pack8(cur batch) -> issue same
// batch of NEXT set into the same av regs (WAR orders issue after the read)
// -> sched_barrier -> 4 MFMAs. Steady state: 12-16 loads (12-16 KB)/wave in
// flight, never draining to 0; 8 waves/CU ~ 128 KB/CU (probe_rw regime).
//
// Stores: SWAPPED MFMA (bfrag first) -> wave w writes cols [32w,32w+32) of
// each of its 16 rows = one full 128B line per row per wave; line-exclusive
// across waves -> no write amplification regardless of wave drift.
// ---------------------------------------------------------------------------
__global__ __launch_bounds__(512) void gemm_kernel(
    const float* __restrict__ h, const short* __restrict__ Bbf,
    const float* __restrict__ pooled, const int* __restrict__ batch,
    float* __restrict__ out) {
  __shared__ float pooled_lds[16 * 256];   // 16 KiB (span <= 16 slice)
  __shared__ short boff_lds[512];          // 1 KiB
  int t    = threadIdx.x;
  int lane = t & 63;
  int w    = t >> 6;                        // 0..7
  const int arow = lane & 15;
  const int kg   = lane >> 4;               // 0..3
  long base_row = (long)blockIdx.x * ROWS_PB;

  // --- B strips for col-tiles 2w, 2w+1 (loaded once, 64 VGPR) ---
  bf16x8 bfrag0[8], bfrag1[8];
#pragma unroll
  for (int ks = 0; ks < 8; ++ks) {
    bfrag0[ks] = *(const bf16x8*)(Bbf + ((((2 * w)     * 8 + ks) * 64 + lane) << 3));
    bfrag1[ks] = *(const bf16x8*)(Bbf + ((((2 * w + 1) * 8 + ks) * 64 + lane) << 3));
  }

  // --- prologue: stage boff + pooled slice into LDS (batch is sorted) ---
  int b_t     = batch[base_row + t];
  int b_first = batch[base_row];
  int b_last  = batch[base_row + ROWS_PB - 1];
  int span    = b_last - b_first + 1;
  boff_lds[t] = (short)(b_t - b_first);
  const bool small_span = (span <= 16);
  if (small_span) {
    int fi = t * 8;                         // 512 threads x 8 floats = 4096
    if (fi < span * H_DIM) {
      *(f32x4*)&pooled_lds[fi]     = *(const f32x4*)(pooled + (long)b_first * H_DIM + fi);
      *(f32x4*)&pooled_lds[fi + 4] = *(const f32x4*)(pooled + (long)b_first * H_DIM + fi + 4);
    }
  }

  // --- set-0 A loads (per-wave private, MFMA fragment pattern) ---
  const float* ap0 = h + (base_row + arow) * H_DIM + (kg << 3);
  f32x4 av[8][2];
#pragma unroll
  for (int ks = 0; ks < 8; ++ks) {
    av[ks][0] = *(const f32x4*)(ap0 + ks * 32);
    av[ks][1] = *(const f32x4*)(ap0 + ks * 32 + 4);
  }

  __syncthreads();                          // the ONLY barrier (LDS staging)

  int o0 = (w << 5) + (kg << 2);            // 32w + 4kg
  int o1 = o0 + 16;

  for (int s = 0; s < NSETS; ++s) {
    long g0 = base_row + (long)s * 16;
    int  sn = (s + 1 < NSETS) ? s + 1 : s;  // clamp: tail re-loads last set
    const float* apn = h + (base_row + (long)sn * 16 + arow) * H_DIM + (kg << 3);

    f32x4 acc0 = {0.f, 0.f, 0.f, 0.f};
    f32x4 acc1 = {0.f, 0.f, 0.f, 0.f};

#pragma unroll
    for (int b = 0; b < 4; ++b) {
      int k0 = 2 * b, k1 = 2 * b + 1;
      // convert current batch (compiler inserts exact vmcnt for these regs)
      bf16x8 af0 = pack8(av[k0][0], av[k0][1]);
      bf16x8 af1 = pack8(av[k1][0], av[k1][1]);
      // issue same batch of NEXT set (WAR on av orders this after pack8)
      av[k0][0] = *(const f32x4*)(apn + k0 * 32);
      av[k0][1] = *(const f32x4*)(apn + k0 * 32 + 4);
      av[k1][0] = *(const f32x4*)(apn + k1 * 32);
      av[k1][1] = *(const f32x4*)(apn + k1 * 32 + 4);
      __builtin_amdgcn_sched_barrier(0);    // loads issued before MFMAs
      acc0 = __builtin_amdgcn_mfma_f32_16x16x32_bf16(bfrag0[k0], af0, acc0, 0, 0, 0);
      acc1 = __builtin_amdgcn_mfma_f32_16x16x32_bf16(bfrag1[k0], af0, acc1, 0, 0, 0);
      acc0 = __builtin_amdgcn_mfma_f32_16x16x32_bf16(bfrag0[k1], af1, acc0, 0, 0, 0);
      acc1 = __builtin_amdgcn_mfma_f32_16x16x32_bf16(bfrag1[k1], af1, acc1, 0, 0, 0);
    }

    // --- epilogue: pv via LDS (no VMEM), line-exclusive stores ---
    int off = (int)boff_lds[s * 16 + arow];
    f32x4 pv0, pv1;
    if (small_span) {
      pv0 = *(const f32x4*)&pooled_lds[(off << 8) + o0];
      pv1 = *(const f32x4*)&pooled_lds[(off << 8) + o1];
    } else {                                // statistically never taken
      const float* pb = pooled + (long)(b_first + off) * H_DIM;
      pv0 = *(const f32x4*)(pb + o0);
      pv1 = *(const f32x4*)(pb + o1);
    }
    float* orow = out + (g0 + arow) * H_DIM;
    *(f32x4*)(orow + o0) = acc0 + pv0;
    *(f32x4*)(orow + o1) = acc1 + pv1;
  }
}

// ---------------------------------------------------------------------------
extern "C" void kernel_launch(void* const* d_in, const int* in_sizes, int n_in,
                              void* d_out, int out_size, void* d_ws, size_t ws_size,
                              hipStream_t stream) {
  const float* h   = (const float*)d_in[0];
  const float* rf  = (const float*)d_in[1];
  const int*   bat = (const int*)d_in[2];
  const float* Wp  = (const float*)d_in[3];
  const float* bp  = (const float*)d_in[4];
  const float* Wl  = (const float*)d_in[5];
  const float* bl  = (const float*)d_in[6];
  float* out = (float*)d_out;

  float* pooled = (float*)d_ws;                          // 64 KiB
  short* Bbf    = (short*)((char*)d_ws + 64 * 1024);     // 128 KiB

  prep_kernel<<<B_SZ + 16, 1024, 0, stream>>>(rf, Wp, bp, Wl, bl, pooled, Bbf);
  gemm_kernel<<<NBLOCKS, 512, 0, stream>>>(h, Bbf, pooled, bat, out);
}

// Round 18
// 147.408 us; speedup vs baseline: 1.9965x; 1.9965x over previous
//
#include <hip/hip_runtime.h>
#include <hip/hip_bf16.h>

// Problem constants
#define N_ATOMS 262144
#define B_SZ    64
#define H_DIM   256
#define R_DIM   512

#define TILE_ROWS 16
#define TPB       32                               // tiles per block
#define NBLOCKS   (N_ATOMS / (TILE_ROWS * TPB))    // 512
#define NBUF      4

typedef __attribute__((ext_vector_type(8))) short bf16x8;
typedef __attribute__((ext_vector_type(4))) float f32x4;

static __device__ __forceinline__ short f2bf(float f) {
  unsigned u = __builtin_bit_cast(unsigned, f);
  u = (u + 0x7FFFu + ((u >> 16) & 1u)) >> 16;   // RNE
  return (short)u;
}

// v_cvt_pk_bf16_f32 (no builtin on gfx950 — inline asm, m240)
static __device__ __forceinline__ unsigned cvtpk(float lo, float hi) {
  unsigned r;
  asm("v_cvt_pk_bf16_f32 %0, %1, %2" : "=v"(r) : "v"(lo), "v"(hi));
  return r;
}

static __device__ __forceinline__ bf16x8 pack8(f32x4 a0, f32x4 a1) {
  unsigned u0 = cvtpk(a0[0], a0[1]);
  unsigned u1 = cvtpk(a0[2], a0[3]);
  unsigned u2 = cvtpk(a1[0], a1[1]);
  unsigned u3 = cvtpk(a1[2], a1[3]);
  bf16x8 v;
  v[0] = (short)(u0 & 0xFFFF); v[1] = (short)(u0 >> 16);
  v[2] = (short)(u1 & 0xFFFF); v[3] = (short)(u1 >> 16);
  v[4] = (short)(u2 & 0xFFFF); v[5] = (short)(u2 >> 16);
  v[6] = (short)(u3 & 0xFFFF); v[7] = (short)(u3 >> 16);
  return v;
}

// async global->LDS DMA, 16B/lane; LDS dest = wave-uniform base + lane*16
static __device__ __forceinline__ void async_copy16(const float* g, short* lds) {
  __builtin_amdgcn_global_load_lds(
      (const __attribute__((address_space(1))) unsigned int*)g,
      (__attribute__((address_space(3))) unsigned int*)lds,
      16, 0, 0);
}

// ---------------------------------------------------------------------------
// Prep kernel (unchanged):
//   blocks [0,64):  pooled[b][o] = bl[o] + retj . Wl[o,256:512]
//   blocks [64,80): Bbf fragment-order bf16 conversion of Wl[:, :256]
// ---------------------------------------------------------------------------
__global__ __launch_bounds__(1024) void prep_kernel(
    const float* __restrict__ rf, const float* __restrict__ Wp,
    const float* __restrict__ bp, const float* __restrict__ Wl,
    const float* __restrict__ bl, float* __restrict__ pooled,
    short* __restrict__ Bbf) {
  int t = threadIdx.x;
  if (blockIdx.x >= B_SZ) {
    int base = (blockIdx.x - B_SZ) * 4096 + t * 4;
#pragma unroll
    for (int q = 0; q < 4; ++q) {
      int idx  = base + q;
      int j    = idx & 7;
      int lane = (idx >> 3) & 63;
      int ks   = (idx >> 9) & 7;
      int ct   = idx >> 12;
      int o    = ct * 16 + (lane & 15);
      int k    = ks * 32 + ((lane >> 4) << 3) + j;
      Bbf[idx] = f2bf(Wl[o * (2 * H_DIM) + k]);
    }
    return;
  }

  __shared__ float meanr[R_DIM];
  __shared__ float retj[H_DIM];
  int b    = blockIdx.x;
  int lane = t & 63;
  int w    = t >> 6;            // 16 waves

  if (t < R_DIM) {
    float s = 0.f;
    const float* p = rf + (long)b * 16 * R_DIM + t;
#pragma unroll
    for (int k = 0; k < 16; ++k) s += p[k * R_DIM];
    meanr[t] = s * (1.f / 16.f);
  }
  __syncthreads();

  {
    f32x4 m0 = *(const f32x4*)&meanr[lane * 8];
    f32x4 m1 = *(const f32x4*)&meanr[lane * 8 + 4];
#pragma unroll
    for (int jj = 0; jj < 16; ++jj) {
      int j = w * 16 + jj;
      const f32x4* wp = (const f32x4*)(Wp + (long)j * R_DIM + lane * 8);
      f32x4 w0 = wp[0], w1 = wp[1];
      float s = m0[0]*w0[0] + m0[1]*w0[1] + m0[2]*w0[2] + m0[3]*w0[3]
              + m1[0]*w1[0] + m1[1]*w1[1] + m1[2]*w1[2] + m1[3]*w1[3];
#pragma unroll
      for (int d = 1; d < 64; d <<= 1) s += __shfl_xor(s, d);
      if (lane == 0) retj[j] = s + bp[j];
    }
  }
  __syncthreads();

  {
    f32x4 r0 = *(const f32x4*)&retj[lane * 4];
#pragma unroll
    for (int oo = 0; oo < 16; ++oo) {
      int o = w * 16 + oo;
      f32x4 wv = *(const f32x4*)(Wl + (long)o * (2 * H_DIM) + H_DIM + lane * 4);
      float s = r0[0]*wv[0] + r0[1]*wv[1] + r0[2]*wv[2] + r0[3]*wv[3];
#pragma unroll
      for (int d = 1; d < 64; d <<= 1) s += __shfl_xor(s, d);
      if (lane == 0) pooled[b * H_DIM + o] = s + bl[o];
    }
  }
}

// ---------------------------------------------------------------------------
// GEMM: out[n][o] = sum_k h[n][k]*Wl[o][k] + pooled[batch[n]][o]
// 512 blocks x 256 threads (4 waves); 32 tiles of 16 rows; 4 LDS A-buffers.
//
// r17 theory (LDS-read amplification is the 144-µs plateau's cause):
// wave col-coverage 64 (4 col-tiles/wave, B = 128 VGPR). Per-wave LDS reads
// 16 KB/tile feed 32 MFMAs -> block amplification 4x (was 8x at 32 cols).
//
// Race-free queue discipline (fixes r15/r17's latent cross-wave race AND
// r17's dummy-DMA bug): per-iter VMEM = exactly {4 DMA, 4 stores}. At end
// of iter t the queue holds DMA(t+1..t+3)=12 + stores(t-2..t)=12 = 24 ops;
// s_waitcnt vmcnt(20) BEFORE the barrier drains exactly DMA(t+1), so after
// the barrier ALL waves' DMA(t+1) stripes are visible to everyone. Still
// >=2 tiles of reads + 3 iters of stores in flight; no vmcnt(0) in loop.
// Tail iters issue dummy DMAs into scratch (wave-uniform dest, never read)
// to keep op counts uniform.
//
// LDS stripe S in [0,16): lane's 16B at S*1024B+lane*16 =
// h[g0+(lane&15)][(S>>1)*32+(lane>>4)*8+(S&1)*4 ..+3]; wave w DMAs stripes
// 4w..4w+3 (src offsets +0,+4,+32,+36 from lsrc). ds_read_b128 lane-linear
// (0 conflicts, verified r4/r8/r15).
// SWAPPED MFMA: row=lane&15, col = ct*16 + (lane>>4)*4 + reg, ct = 4w+ci ->
// wave w writes cols [64w,64w+64) of each row: 4 dwordx4/thread, two full
// 128B lines per row per wave, line-exclusive across waves.
// ---------------------------------------------------------------------------
__global__ __launch_bounds__(256, 2) void gemm_kernel(
    const float* __restrict__ h, const short* __restrict__ Bbf,
    const float* __restrict__ pooled, const int* __restrict__ batch,
    float* __restrict__ out) {
  __shared__ short As[NBUF][16 * 512];     // 64 KiB
  __shared__ float pooled_lds[8 * 256];    // 8 KiB (span <= 8 slice)
  __shared__ short boff_lds[512];          // 1 KiB
  __shared__ short scratch[512];           // 1 KiB (dummy DMA dest)
  int t    = threadIdx.x;
  int lane = t & 63;
  int w    = t >> 6;                        // 0..3
  const int arow = lane & 15;
  const int kg   = lane >> 4;               // 0..3

  // --- B strips for col-tiles 4w..4w+3 (loaded once, 128 VGPR) ---
  bf16x8 bfrag[4][8];
#pragma unroll
  for (int ci = 0; ci < 4; ++ci)
#pragma unroll
    for (int ks = 0; ks < 8; ++ks)
      bfrag[ci][ks] = *(const bf16x8*)(
          Bbf + ((((4 * w + ci) * 8 + ks) * 64 + lane) << 3));

  long base_row = (long)blockIdx.x * (TILE_ROWS * TPB);   // 512 rows/block
  // wave w's per-lane global src offset within a tile (stripes 4w..4w+3)
  const long lsrc = (long)arow * H_DIM + (w << 6) + (kg << 3);

  // --- prologue: stage boff + pooled slice + A tiles 0..2 ---
  int b_t     = batch[base_row + t];
  int b_t2    = batch[base_row + 256 + t];
  int b_first = batch[base_row];
  int b_last  = batch[base_row + TILE_ROWS * TPB - 1];
  int span    = b_last - b_first + 1;
  boff_lds[t]       = (short)(b_t  - b_first);
  boff_lds[t + 256] = (short)(b_t2 - b_first);
  const bool small_span = (span <= 8);
  if (small_span) {
    int fi = t * 8;                         // 256 threads x 8 floats = 2048
    if (fi < span * H_DIM) {
      *(f32x4*)&pooled_lds[fi]     = *(const f32x4*)(pooled + (long)b_first * H_DIM + fi);
      *(f32x4*)&pooled_lds[fi + 4] = *(const f32x4*)(pooled + (long)b_first * H_DIM + fi + 4);
    }
  }
#pragma unroll
  for (int tl = 0; tl < 3; ++tl) {
    const float* gp = h + (base_row + (long)tl * TILE_ROWS) * H_DIM + lsrc;
    short* d = &As[tl][0];
    async_copy16(gp,      d + (4 * w)     * 512);
    async_copy16(gp + 4,  d + (4 * w + 1) * 512);
    async_copy16(gp + 32, d + (4 * w + 2) * 512);
    async_copy16(gp + 36, d + (4 * w + 3) * 512);
  }
  __syncthreads();                          // full drain once (prologue only)

  for (int tt = 0; tt < TPB; ++tt) {
    long g0 = base_row + (long)tt * TILE_ROWS;

    // --- (1) DMA(t+3), or dummy into scratch (uniform 4 ops every iter) ---
    {
      const float* gp;
      short *d0, *d1, *d2, *d3;
      if (tt + 3 < TPB) {
        gp = h + (g0 + 3 * TILE_ROWS) * H_DIM + lsrc;
        short* d = &As[(tt + 3) & 3][0];
        d0 = d + (4 * w)     * 512;
        d1 = d + (4 * w + 1) * 512;
        d2 = d + (4 * w + 2) * 512;
        d3 = d + (4 * w + 3) * 512;
      } else {
        gp = h + base_row * H_DIM + lsrc;   // any valid address
        d0 = d1 = d2 = d3 = scratch;        // wave-uniform, never read
      }
      async_copy16(gp,      d0);
      async_copy16(gp + 4,  d1);
      async_copy16(gp + 32, d2);
      async_copy16(gp + 36, d3);
    }
    __builtin_amdgcn_sched_barrier(0);

    // --- (2) compute tile t from As[tt&3]: 16 ds_read -> 32 MFMA ---
    // (landed: prologue drain for tt<=2; prev iter's vmcnt(20)+barrier else)
    const short* ab = &As[tt & 3][0];
    f32x4 acc0 = {0.f, 0.f, 0.f, 0.f};
    f32x4 acc1 = {0.f, 0.f, 0.f, 0.f};
    f32x4 acc2 = {0.f, 0.f, 0.f, 0.f};
    f32x4 acc3 = {0.f, 0.f, 0.f, 0.f};
#pragma unroll
    for (int ks = 0; ks < 8; ++ks) {
      f32x4 v0 = *(const f32x4*)(ab + ks * 1024 + lane * 8);
      f32x4 v1 = *(const f32x4*)(ab + ks * 1024 + 512 + lane * 8);
      bf16x8 af = pack8(v0, v1);
      acc0 = __builtin_amdgcn_mfma_f32_16x16x32_bf16(bfrag[0][ks], af, acc0, 0, 0, 0);
      acc1 = __builtin_amdgcn_mfma_f32_16x16x32_bf16(bfrag[1][ks], af, acc1, 0, 0, 0);
      acc2 = __builtin_amdgcn_mfma_f32_16x16x32_bf16(bfrag[2][ks], af, acc2, 0, 0, 0);
      acc3 = __builtin_amdgcn_mfma_f32_16x16x32_bf16(bfrag[3][ks], af, acc3, 0, 0, 0);
    }

    // --- (3) pv via LDS (no VMEM) + 4 line-exclusive stores ---
    int off = (int)boff_lds[tt * 16 + arow];
    const float* pl = small_span ? &pooled_lds[off << 8]
                                 : pooled + (long)(b_first + off) * H_DIM;
    float* orow = out + (g0 + arow) * H_DIM;
    {
      int o = (w << 6) + (kg << 2);
      *(f32x4*)(orow + o)      = acc0 + *(const f32x4*)(pl + o);
      *(f32x4*)(orow + o + 16) = acc1 + *(const f32x4*)(pl + o + 16);
      *(f32x4*)(orow + o + 32) = acc2 + *(const f32x4*)(pl + o + 32);
      *(f32x4*)(orow + o + 48) = acc3 + *(const f32x4*)(pl + o + 48);
    }

    // --- (4) race-free handoff: drain DMA(t+1) in EVERY wave, THEN barrier.
    // Queue at this point: DMA(t+1..t+3)=12 + stores(t-2..t)=12 = 24 ops;
    // vmcnt(20) drains exactly the 4 DMA(t+1) ops (and all older).
    asm volatile("s_waitcnt vmcnt(20)" ::: "memory");
    __builtin_amdgcn_s_barrier();
    __builtin_amdgcn_sched_barrier(0);
  }
}

// ---------------------------------------------------------------------------
extern "C" void kernel_launch(void* const* d_in, const int* in_sizes, int n_in,
                              void* d_out, int out_size, void* d_ws, size_t ws_size,
                              hipStream_t stream) {
  const float* h   = (const float*)d_in[0];
  const float* rf  = (const float*)d_in[1];
  const int*   bat = (const int*)d_in[2];
  const float* Wp  = (const float*)d_in[3];
  const float* bp  = (const float*)d_in[4];
  const float* Wl  = (const float*)d_in[5];
  const float* bl  = (const float*)d_in[6];
  float* out = (float*)d_out;

  float* pooled = (float*)d_ws;                          // 64 KiB
  short* Bbf    = (short*)((char*)d_ws + 64 * 1024);     // 128 KiB

  prep_kernel<<<B_SZ + 16, 1024, 0, stream>>>(rf, Wp, bp, Wl, bl, pooled, Bbf);
  gemm_kernel<<<NBLOCKS, 256, 0, stream>>>(h, Bbf, pooled, bat, out);
}